// Round 10
// baseline (191.691 us; speedup 1.0000x reference)
//
#include <hip/hip_runtime.h>
#include <math.h>

constexpr int D    = 128;
constexpr int BT   = 128;    // targets per bucket (bucket = tgt >> 7)
constexpr int TILE = 4096;   // edges per bucketize block

using bf16x8 = __attribute__((ext_vector_type(8))) short;
using f32x4  = __attribute__((ext_vector_type(4))) float;
#define MFMA16 __builtin_amdgcn_mfma_f32_16x16x32_bf16

__device__ __forceinline__ unsigned short f2bf(float f) {
    unsigned u = __builtin_bit_cast(unsigned, f);
    u = (u + 0x7FFF + ((u >> 16) & 1)) >> 16;   // RNE
    return (unsigned short)u;
}

// ---------------------------------------------------------------------------
// wprod: Wlp = Wl@Wp, Wrp = Wr@Wp in MFMA B-frag bf16 layout; cvec = bl@Wp+bp.
// grid = 16 (2 mats x 8 col-groups of 16) -- kills r9's 2-block serial head.
// Wm staged in LDS with 129-pad (conflict-free column reads), Wp cols in LDS.
// Blocks 0..3 also zero zl's sentinel row N (per slice).
// ---------------------------------------------------------------------------
__global__ __launch_bounds__(256)
void wprod_kernel(const float* __restrict__ Wl, const float* __restrict__ Wr,
                  const float* __restrict__ Wp,
                  const float* __restrict__ bl, const float* __restrict__ bp,
                  unsigned short* __restrict__ WlpB, unsigned short* __restrict__ WrpB,
                  float* __restrict__ cvec, unsigned short* __restrict__ zl, int N)
{
    __shared__ float wm[128 * 129];   // 66 KB, pad -> bank (r+k)&31
    __shared__ float wpc[128 * 16];   // 8 KB: Wp[:, c0..c0+16)

    const int bid = blockIdx.x;
    const int m   = bid >> 3;         // 0 = Wl, 1 = Wr
    const int cg  = bid & 7;
    const int c0  = cg * 16;
    const float* Wm = m ? Wr : Wl;
    unsigned short* OB = m ? WrpB : WlpB;
    const int t = threadIdx.x;

    // zero zl sentinel rows (slice s row N, 32 ushorts each)
    if (bid < 4 && t < 32)
        zl[((size_t)bid * (N + 1) + N) * 32 + t] = 0;

    for (int i = t; i < 128 * 128; i += 256) {
        int r = i >> 7, k = i & 127;
        wm[r * 129 + k] = Wm[i];
    }
    for (int i = t; i < 2048; i += 256) {
        int k = i >> 4, col = i & 15;
        wpc[i] = Wp[k * 128 + c0 + col];
    }
    __syncthreads();

    const int r = t >> 1;             // row 0..127
    const int h = (t & 1) * 8;        // col half within 16
    float acc[8];
    #pragma unroll
    for (int j = 0; j < 8; ++j) acc[j] = 0.f;

    for (int k = 0; k < 128; ++k) {
        float wv = wm[r * 129 + k];
        #pragma unroll
        for (int j = 0; j < 8; ++j) acc[j] += wv * wpc[k * 16 + h + j];
    }

    // frag layout: row=kt*32+(l>>4)*8+jj, col=nt*16+(l&15); here nt==cg.
    const int kt = r >> 5, lhi = (r >> 3) & 3, jj = r & 7;
    #pragma unroll
    for (int j = 0; j < 8; ++j) {
        int l = lhi * 16 + h + j;
        OB[((size_t)(kt * 8 + cg) * 64 + l) * 8 + jj] = f2bf(acc[j]);
    }

    if (m == 0 && t < 16) {
        int c = c0 + t;
        float s = bp[c];
        for (int k = 0; k < 128; ++k) s += bl[k] * wpc[k * 16 + t];
        cvec[c] = s;
    }
}

// ---------------------------------------------------------------------------
// prep: [0,GA+GB) bucketize edges; [GA+GB,+GCONV) x f32 -> bf16 ROW-major.
// ---------------------------------------------------------------------------
__global__ __launch_bounds__(256)
void prep_kernel(const float* __restrict__ x, unsigned short* __restrict__ x_bf,
                 const int* __restrict__ ea, int Ea,
                 const int* __restrict__ eb, int Eb,
                 unsigned int* __restrict__ ent_a, int* __restrict__ cnt_a,
                 unsigned int* __restrict__ ent_b, int* __restrict__ cnt_b,
                 int N, int NBKT, int CAP, int GA, int GB, int GCONV)
{
    __shared__ int hist[512];
    __shared__ int base[512];

    const int bid = blockIdx.x;
    const int t   = threadIdx.x;

    if (bid < GA + GB) {
        const int type = (bid >= GA);
        const int* e   = type ? eb : ea;
        const int  E   = type ? Eb : Ea;
        unsigned int* ent = type ? ent_b : ent_a;
        int* cnt          = type ? cnt_b : cnt_a;
        const int i0 = (bid - type * GA) * TILE;

        for (int h = t; h < NBKT; h += 256) hist[h] = 0;
        __syncthreads();

        int tgts[16];
        #pragma unroll
        for (int j = 0; j < 16; ++j) {
            int i = i0 + j * 256 + t;
            tgts[j] = (i < E) ? e[(size_t)E + i] : -1;
            if (tgts[j] >= 0) atomicAdd(&hist[tgts[j] >> 7], 1);
        }
        __syncthreads();

        for (int h = t; h < NBKT; h += 256) {
            base[h] = (hist[h] > 0) ? atomicAdd(&cnt[h], hist[h]) : 0;
            hist[h] = 0;
        }
        __syncthreads();

        #pragma unroll
        for (int j = 0; j < 16; ++j) {
            int i = i0 + j * 256 + t;
            if (tgts[j] >= 0) {
                int b   = tgts[j] >> 7;
                int pos = base[b] + atomicAdd(&hist[b], 1);
                if (pos < CAP)
                    ent[(size_t)b * CAP + pos] = ((unsigned)e[i] << 7) | (tgts[j] & 127);
            }
        }
    } else {
        const int total4 = N * 32;            // float4s
        for (int i = (bid - GA - GB) * 256 + t; i < total4; i += GCONV * 256) {
            float4 v = reinterpret_cast<const float4*>(x)[i];
            ushort4 o;
            o.x = f2bf(v.x); o.y = f2bf(v.y); o.z = f2bf(v.z); o.w = f2bf(v.w);
            reinterpret_cast<ushort4*>(x_bf)[i] = o;
        }
    }
}

// ---------------------------------------------------------------------------
// sort: per (type,bucket): LDS histogram + scan + scatter; persist sorted
// src list (ushort) + per-node offsets. (unchanged, verified r6-r9)
// ---------------------------------------------------------------------------
__global__ __launch_bounds__(512)
void sort_kernel(const unsigned int* __restrict__ ent_a, const int* __restrict__ cnt_a,
                 const unsigned int* __restrict__ ent_b, const int* __restrict__ cnt_b,
                 unsigned short* __restrict__ srcl_g, int* __restrict__ off_g,
                 int NBKT, int CAP)
{
    extern __shared__ __align__(16) char smem_raw[];
    int* tmp  = (int*)smem_raw;                          // CAP
    int* off  = tmp + CAP;                               // BT+1
    int* cur  = off + BT + 1;                            // BT
    int* wtot = cur + BT;                                // 2
    unsigned short* srcl = (unsigned short*)(wtot + 2);  // CAP

    const int bid  = blockIdx.x;
    const int type = (bid >= NBKT);
    const int k    = bid - type * NBKT;
    const unsigned int* ent = type ? ent_b : ent_a;
    const int cnt = min((type ? cnt_b : cnt_a)[k], CAP);

    const int t = threadIdx.x, l = t & 63, w = t >> 6;

    if (t < BT) off[t] = 0;
    __syncthreads();

    for (int i = t; i < cnt; i += 512) {
        unsigned e = ent[(size_t)k * CAP + i];
        tmp[i] = (int)e;
        atomicAdd(&off[e & (BT - 1)], 1);
    }
    __syncthreads();

    int v = 0, s = 0;
    if (t < BT) {
        v = off[t]; s = v;
        #pragma unroll
        for (int o = 1; o < 64; o <<= 1) {
            int u = __shfl_up(s, o, 64);
            if (l >= o) s += u;
        }
        if (l == 63) wtot[w] = s;
    }
    __syncthreads();
    if (t < BT) {
        int ex = ((w == 1) ? wtot[0] : 0) + s - v;
        off[t] = ex; cur[t] = ex;
    }
    if (t == 0) off[BT] = wtot[0] + wtot[1];
    __syncthreads();

    for (int i = t; i < cnt; i += 512) {
        unsigned e = (unsigned)tmp[i];
        int pos = atomicAdd(&cur[e & (BT - 1)], 1);
        srcl[pos] = (unsigned short)(e >> 7);
    }
    __syncthreads();

    for (int i = t; i < cnt; i += 512)
        srcl_g[(size_t)bid * CAP + i] = srcl[i];
    if (t <= BT)
        off_g[(size_t)bid * (BT + 1) + t] = off[t];
}

// ---------------------------------------------------------------------------
// gemmZ: Z_l = x@Wlp (SLICE-major bf16 [4][N+1][32]; row N = sentinel zeros),
//        Z_r = x@Wrp + cvec (row-major bf16).
// ---------------------------------------------------------------------------
__global__ __launch_bounds__(256)
void gemmz_kernel(const unsigned short* __restrict__ x_bf,
                  const unsigned short* __restrict__ WlpB,
                  const unsigned short* __restrict__ WrpB,
                  const float* __restrict__ cvec,
                  unsigned short* __restrict__ zl, unsigned short* __restrict__ zr,
                  int N)
{
    const int t = threadIdx.x, w = t >> 6, l = t & 63;
    const int q = l & 15, kg = l >> 4;
    const int node0 = blockIdx.x * 64 + w * 16;
    const int arow = min(node0 + q, N - 1);

    bf16x8 fx[4];
    #pragma unroll
    for (int kt = 0; kt < 4; ++kt)
        fx[kt] = *reinterpret_cast<const bf16x8*>(x_bf + (size_t)arow * D + kt * 32 + kg * 8);

    #pragma unroll
    for (int nt = 0; nt < 8; ++nt) {
        f32x4 cl = {0.f, 0.f, 0.f, 0.f};
        f32x4 cr = {0.f, 0.f, 0.f, 0.f};
        #pragma unroll
        for (int kt = 0; kt < 4; ++kt) {
            const size_t fo = ((size_t)(kt * 8 + nt) * 64 + l) * 8;
            bf16x8 wl = *reinterpret_cast<const bf16x8*>(WlpB + fo);
            bf16x8 wr = *reinterpret_cast<const bf16x8*>(WrpB + fo);
            cl = MFMA16(fx[kt], wl, cl, 0, 0, 0);
            cr = MFMA16(fx[kt], wr, cr, 0, 0, 0);
        }
        float cv = cvec[nt * 16 + q];
        const int sidx = nt >> 1;
        const int cin  = (nt & 1) * 16 + q;
        #pragma unroll
        for (int r = 0; r < 4; ++r) {
            int grow = node0 + kg * 4 + r;
            if (grow < N) {
                zl[((size_t)sidx * (N + 1) + grow) * 32 + cin] = f2bf(cl[r]);
                zr[(size_t)grow * D + nt * 16 + q]             = f2bf(cr[r] + cv);
            }
        }
    }
}

// ---------------------------------------------------------------------------
// gather: grid = 4 slices x 2 types x NBKT (slice = bid&3 -> one 3.2MB slice
// per XCD, L2-resident). ILP FIX vs r9 (VGPR=24 => ILP~1): branchless batch-8
// with explicit vv[8] arrays; out-of-degree slots select the SENTINEL zero
// row N (unconditional load+add of zeros). Compiler must hold 8 loads in
// flight -> VGPR ~40+, C ~ 5 waves x 8.
// ---------------------------------------------------------------------------
__global__ __launch_bounds__(256)
void gather_kernel(const unsigned* __restrict__ zl,       // [4][N+1][16] dwords
                   const unsigned short* __restrict__ srcl_g,
                   const int* __restrict__ off_g,
                   unsigned short* __restrict__ agg_a,
                   unsigned short* __restrict__ agg_b,
                   int N, int NBKT, int CAP)
{
    extern __shared__ __align__(16) char smem_raw[];
    int* off = (int*)smem_raw;                               // BT+1
    unsigned short* srcl = (unsigned short*)(off + BT + 1);  // CAP+64

    const int bid   = blockIdx.x;
    const int slice = bid & 3;
    const int tb    = bid >> 2;
    const int type  = (tb >= NBKT);
    const int k     = tb - type * NBKT;

    const int t = threadIdx.x, l = t & 63, w = t >> 6;
    const int q = l >> 4;                      // node within wave quad
    const unsigned c = l & 15;                 // dword within 64B slice row

    const int cnt = off_g[(size_t)tb * (BT + 1) + BT];
    for (int i = t; i <= BT; i += 256)
        off[i] = off_g[(size_t)tb * (BT + 1) + i];
    for (int i = t; i < cnt; i += 256)
        srcl[i] = srcl_g[(size_t)tb * CAP + i];
    for (int i = cnt + t; i < cnt + 64; i += 256)
        srcl[i] = 0;                           // pad so batch reads stay in-array
    __syncthreads();

    const unsigned* zs = zl + (size_t)slice * (N + 1) * 16;
    unsigned short* agg = (type ? agg_b : agg_a) + (size_t)slice * N * 32;
    const unsigned ZROW = (unsigned)N;         // sentinel zero row

    for (int pass = 0; pass < BT / 16; ++pass) {
        const int tt = pass * 16 + w * 4 + q;
        const int o0 = off[tt], o1 = off[tt + 1];
        const int deg = o1 - o0;
        int md = max(deg, __shfl_xor(deg, 16, 64));
        md = max(md, __shfl_xor(md, 32, 64));

        float a0 = 0.f, a1 = 0.f;
        for (int j = 0; j < md; j += 8) {
            unsigned vv[8];
            #pragma unroll
            for (int kk = 0; kk < 8; ++kk) {
                int jj = j + kk;
                unsigned sid = srcl[o0 + jj];          // in-array (padded)
                sid = (jj < deg) ? sid : ZROW;         // sentinel select
                vv[kk] = zs[sid * 16 + c];
            }
            #pragma unroll
            for (int kk = 0; kk < 8; ++kk) {
                a0 += __builtin_bit_cast(float, vv[kk] << 16);
                a1 += __builtin_bit_cast(float, vv[kk] & 0xffff0000u);
            }
        }
        const float r = 1.0f / fmaxf((float)deg, 1.0f);
        const int n = k * BT + tt;
        if (n < N) {
            unsigned o = ((unsigned)f2bf(a1 * r) << 16) | f2bf(a0 * r);
            *(unsigned*)(agg + (size_t)n * 32 + c * 2) = o;
        }
    }
}

// ---------------------------------------------------------------------------
// epilogue: logits_t = agg_t + Z_r; softmax over 128 cols (16 lanes x 8),
// average the two edge types, store f32. (unchanged, verified r9)
// ---------------------------------------------------------------------------
__global__ __launch_bounds__(256)
void epi_kernel(const unsigned short* __restrict__ agg_a,
                const unsigned short* __restrict__ agg_b,
                const unsigned short* __restrict__ zr,
                float* __restrict__ out, int N)
{
    const int t = threadIdx.x;
    const int n = blockIdx.x * 16 + (t >> 4);
    const int c = t & 15;
    if (n >= N) return;

    const int s = c >> 2;
    const size_t aoff = ((size_t)s * N + n) * 32 + (c & 3) * 8;   // ushort idx
    uint4 va = *reinterpret_cast<const uint4*>(agg_a + aoff);
    uint4 vb = *reinterpret_cast<const uint4*>(agg_b + aoff);
    uint4 vz = *reinterpret_cast<const uint4*>(zr + (size_t)n * D + c * 8);

    unsigned ua[4] = {va.x, va.y, va.z, va.w};
    unsigned ub[4] = {vb.x, vb.y, vb.z, vb.w};
    unsigned uz[4] = {vz.x, vz.y, vz.z, vz.w};

    float la[8], lb[8];
    #pragma unroll
    for (int d = 0; d < 4; ++d) {
        float z0 = __builtin_bit_cast(float, uz[d] << 16);
        float z1 = __builtin_bit_cast(float, uz[d] & 0xffff0000u);
        la[2*d]   = __builtin_bit_cast(float, ua[d] << 16) + z0;
        la[2*d+1] = __builtin_bit_cast(float, ua[d] & 0xffff0000u) + z1;
        lb[2*d]   = __builtin_bit_cast(float, ub[d] << 16) + z0;
        lb[2*d+1] = __builtin_bit_cast(float, ub[d] & 0xffff0000u) + z1;
    }

    float ma = -INFINITY, mb = -INFINITY;
    #pragma unroll
    for (int j = 0; j < 8; ++j) { ma = fmaxf(ma, la[j]); mb = fmaxf(mb, lb[j]); }
    #pragma unroll
    for (int o = 1; o < 16; o <<= 1) {
        ma = fmaxf(ma, __shfl_xor(ma, o, 64));
        mb = fmaxf(mb, __shfl_xor(mb, o, 64));
    }
    float sa = 0.f, sb = 0.f;
    #pragma unroll
    for (int j = 0; j < 8; ++j) {
        la[j] = __expf(la[j] - ma); sa += la[j];
        lb[j] = __expf(lb[j] - mb); sb += lb[j];
    }
    #pragma unroll
    for (int o = 1; o < 16; o <<= 1) {
        sa += __shfl_xor(sa, o, 64);
        sb += __shfl_xor(sb, o, 64);
    }
    const float ra = 0.5f / sa, rb = 0.5f / sb;

    float4 o0, o1;
    o0.x = la[0]*ra + lb[0]*rb; o0.y = la[1]*ra + lb[1]*rb;
    o0.z = la[2]*ra + lb[2]*rb; o0.w = la[3]*ra + lb[3]*rb;
    o1.x = la[4]*ra + lb[4]*rb; o1.y = la[5]*ra + lb[5]*rb;
    o1.z = la[6]*ra + lb[6]*rb; o1.w = la[7]*ra + lb[7]*rb;
    float* op = out + (size_t)n * D + c * 8;
    *reinterpret_cast<float4*>(op)     = o0;
    *reinterpret_cast<float4*>(op + 4) = o1;
}

// ---------------------------------------------------------------------------
extern "C" void kernel_launch(void* const* d_in, const int* in_sizes, int n_in,
                              void* d_out, int out_size, void* d_ws, size_t ws_size,
                              hipStream_t stream)
{
    const float* x  = (const float*)d_in[0];
    const float* Wl = (const float*)d_in[1];
    const float* bl = (const float*)d_in[2];
    const float* Wr = (const float*)d_in[3];
    const float* Wp = (const float*)d_in[4];
    const float* bp = (const float*)d_in[5];
    const int*   ea = (const int*)d_in[6];
    const int*   eb = (const int*)d_in[7];

    const int N  = in_sizes[0] / D;
    const int Ea = in_sizes[6] / 2;
    const int Eb = in_sizes[7] / 2;

    const int NBKT = (N + BT - 1) / BT;
    const int Emax = Ea > Eb ? Ea : Eb;
    int CAP = (int)(((long long)Emax * BT / N) * 5 / 4 + 128);
    CAP = (CAP + 7) & ~7;

    unsigned int* ent_a = (unsigned int*)d_ws;              // NBKT*CAP
    unsigned int* ent_b = ent_a + (size_t)NBKT * CAP;
    int* cnt_a = (int*)(ent_b + (size_t)NBKT * CAP);        // NBKT
    int* cnt_b = cnt_a + NBKT;
    int* off_g = cnt_b + NBKT;                              // 2*NBKT*(BT+1)
    float* cvec = (float*)(off_g + (size_t)2 * NBKT * (BT + 1));  // 128
    uintptr_t p = (uintptr_t)(cvec + 128);
    p = (p + 15) & ~(uintptr_t)15;
    unsigned short* srcl_g = (unsigned short*)p;            // 2*NBKT*CAP
    unsigned short* x_bf   = srcl_g + (size_t)2 * NBKT * CAP;
    unsigned short* zl     = x_bf + (size_t)N * D;          // [4][N+1][32]
    unsigned short* zr     = zl + (size_t)4 * (N + 1) * 32; // row-major
    unsigned short* agg_a  = zr + (size_t)N * D;            // slice-major [4][N][32]
    unsigned short* agg_b  = agg_a + (size_t)N * D;
    unsigned short* WlpB   = agg_b + (size_t)N * D;         // frag layout
    unsigned short* WrpB   = WlpB + D * D;

    hipMemsetAsync(cnt_a, 0, sizeof(int) * 2 * (size_t)NBKT, stream);

    wprod_kernel<<<16, 256, 0, stream>>>(Wl, Wr, Wp, bl, bp, WlpB, WrpB,
                                         cvec, zl, N);

    const int GA = (Ea + TILE - 1) / TILE;
    const int GB = (Eb + TILE - 1) / TILE;
    const int GCONV = 512;
    prep_kernel<<<GA + GB + GCONV, 256, 0, stream>>>(
        x, x_bf, ea, Ea, eb, Eb, ent_a, cnt_a, ent_b, cnt_b,
        N, NBKT, CAP, GA, GB, GCONV);

    const int smem_sort = CAP * 6 + (BT + 1 + BT + 2) * 4 + 16;
    sort_kernel<<<2 * NBKT, 512, smem_sort, stream>>>(
        ent_a, cnt_a, ent_b, cnt_b, srcl_g, off_g, NBKT, CAP);

    gemmz_kernel<<<(N + 63) / 64, 256, 0, stream>>>(
        x_bf, WlpB, WrpB, cvec, zl, zr, N);

    const int smem_gather = (BT + 1) * 4 + (CAP + 64) * 2 + 16;
    gather_kernel<<<8 * NBKT, 256, smem_gather, stream>>>(
        (const unsigned*)zl, srcl_g, off_g, agg_a, agg_b, N, NBKT, CAP);

    epi_kernel<<<(N + 15) / 16, 256, 0, stream>>>(agg_a, agg_b, zr,
                                                  (float*)d_out, N);
}

// Round 11
// 137.998 us; speedup vs baseline: 1.3891x; 1.3891x over previous
//
#include <hip/hip_runtime.h>
#include <math.h>

constexpr int D    = 128;
constexpr int BT   = 128;    // targets per bucket (bucket = tgt >> 7)
constexpr int TILE = 4096;   // edges per bucketize block
constexpr int CE   = 256;    // edges per gather chunk

using bf16x8 = __attribute__((ext_vector_type(8))) short;
using f32x4  = __attribute__((ext_vector_type(4))) float;
#define MFMA16 __builtin_amdgcn_mfma_f32_16x16x32_bf16

__device__ __forceinline__ unsigned short f2bf(float f) {
    unsigned u = __builtin_bit_cast(unsigned, f);
    u = (u + 0x7FFF + ((u >> 16) & 1)) >> 16;   // RNE
    return (unsigned short)u;
}

// ---------------------------------------------------------------------------
// wprod: Wlp = Wl@Wp, Wrp = Wr@Wp in MFMA B-frag bf16 layout; cvec = bl@Wp+bp.
// grid = 16 (2 mats x 8 col-groups of 16).
// ---------------------------------------------------------------------------
__global__ __launch_bounds__(256)
void wprod_kernel(const float* __restrict__ Wl, const float* __restrict__ Wr,
                  const float* __restrict__ Wp,
                  const float* __restrict__ bl, const float* __restrict__ bp,
                  unsigned short* __restrict__ WlpB, unsigned short* __restrict__ WrpB,
                  float* __restrict__ cvec)
{
    __shared__ float wm[128 * 129];
    __shared__ float wpc[128 * 16];

    const int bid = blockIdx.x;
    const int m   = bid >> 3;
    const int cg  = bid & 7;
    const int c0  = cg * 16;
    const float* Wm = m ? Wr : Wl;
    unsigned short* OB = m ? WrpB : WlpB;
    const int t = threadIdx.x;

    for (int i = t; i < 128 * 128; i += 256) {
        int r = i >> 7, k = i & 127;
        wm[r * 129 + k] = Wm[i];
    }
    for (int i = t; i < 2048; i += 256) {
        int k = i >> 4, col = i & 15;
        wpc[i] = Wp[k * 128 + c0 + col];
    }
    __syncthreads();

    const int r = t >> 1;
    const int h = (t & 1) * 8;
    float acc[8];
    #pragma unroll
    for (int j = 0; j < 8; ++j) acc[j] = 0.f;

    for (int k = 0; k < 128; ++k) {
        float wv = wm[r * 129 + k];
        #pragma unroll
        for (int j = 0; j < 8; ++j) acc[j] += wv * wpc[k * 16 + h + j];
    }

    const int kt = r >> 5, lhi = (r >> 3) & 3, jj = r & 7;
    #pragma unroll
    for (int j = 0; j < 8; ++j) {
        int l = lhi * 16 + h + j;
        OB[((size_t)(kt * 8 + cg) * 64 + l) * 8 + jj] = f2bf(acc[j]);
    }

    if (m == 0 && t < 16) {
        int c = c0 + t;
        float s = bp[c];
        for (int k = 0; k < 128; ++k) s += bl[k] * wpc[k * 16 + t];
        cvec[c] = s;
    }
}

// ---------------------------------------------------------------------------
// prep: [0,GA+GB) bucketize edges; [GA+GB,+GCONV) x f32 -> bf16 ROW-major.
// ---------------------------------------------------------------------------
__global__ __launch_bounds__(256)
void prep_kernel(const float* __restrict__ x, unsigned short* __restrict__ x_bf,
                 const int* __restrict__ ea, int Ea,
                 const int* __restrict__ eb, int Eb,
                 unsigned int* __restrict__ ent_a, int* __restrict__ cnt_a,
                 unsigned int* __restrict__ ent_b, int* __restrict__ cnt_b,
                 int N, int NBKT, int CAP, int GA, int GB, int GCONV)
{
    __shared__ int hist[512];
    __shared__ int base[512];

    const int bid = blockIdx.x;
    const int t   = threadIdx.x;

    if (bid < GA + GB) {
        const int type = (bid >= GA);
        const int* e   = type ? eb : ea;
        const int  E   = type ? Eb : Ea;
        unsigned int* ent = type ? ent_b : ent_a;
        int* cnt          = type ? cnt_b : cnt_a;
        const int i0 = (bid - type * GA) * TILE;

        for (int h = t; h < NBKT; h += 256) hist[h] = 0;
        __syncthreads();

        int tgts[16];
        #pragma unroll
        for (int j = 0; j < 16; ++j) {
            int i = i0 + j * 256 + t;
            tgts[j] = (i < E) ? e[(size_t)E + i] : -1;
            if (tgts[j] >= 0) atomicAdd(&hist[tgts[j] >> 7], 1);
        }
        __syncthreads();

        for (int h = t; h < NBKT; h += 256) {
            base[h] = (hist[h] > 0) ? atomicAdd(&cnt[h], hist[h]) : 0;
            hist[h] = 0;
        }
        __syncthreads();

        #pragma unroll
        for (int j = 0; j < 16; ++j) {
            int i = i0 + j * 256 + t;
            if (tgts[j] >= 0) {
                int b   = tgts[j] >> 7;
                int pos = base[b] + atomicAdd(&hist[b], 1);
                if (pos < CAP)
                    ent[(size_t)b * CAP + pos] = ((unsigned)e[i] << 7) | (tgts[j] & 127);
            }
        }
    } else {
        const int total4 = N * 32;
        for (int i = (bid - GA - GB) * 256 + t; i < total4; i += GCONV * 256) {
            float4 v = reinterpret_cast<const float4*>(x)[i];
            ushort4 o;
            o.x = f2bf(v.x); o.y = f2bf(v.y); o.z = f2bf(v.z); o.w = f2bf(v.w);
            reinterpret_cast<ushort4*>(x_bf)[i] = o;
        }
    }
}

// ---------------------------------------------------------------------------
// sort: per (type,bucket): LDS histogram + scan + scatter; persist sorted
// src list (ushort) + per-node offsets. (verified r6-r10)
// ---------------------------------------------------------------------------
__global__ __launch_bounds__(512)
void sort_kernel(const unsigned int* __restrict__ ent_a, const int* __restrict__ cnt_a,
                 const unsigned int* __restrict__ ent_b, const int* __restrict__ cnt_b,
                 unsigned short* __restrict__ srcl_g, int* __restrict__ off_g,
                 int NBKT, int CAP)
{
    extern __shared__ __align__(16) char smem_raw[];
    int* tmp  = (int*)smem_raw;                          // CAP
    int* off  = tmp + CAP;                               // BT+1
    int* cur  = off + BT + 1;                            // BT
    int* wtot = cur + BT;                                // 2
    unsigned short* srcl = (unsigned short*)(wtot + 2);  // CAP

    const int bid  = blockIdx.x;
    const int type = (bid >= NBKT);
    const int k    = bid - type * NBKT;
    const unsigned int* ent = type ? ent_b : ent_a;
    const int cnt = min((type ? cnt_b : cnt_a)[k], CAP);

    const int t = threadIdx.x, l = t & 63, w = t >> 6;

    if (t < BT) off[t] = 0;
    __syncthreads();

    for (int i = t; i < cnt; i += 512) {
        unsigned e = ent[(size_t)k * CAP + i];
        tmp[i] = (int)e;
        atomicAdd(&off[e & (BT - 1)], 1);
    }
    __syncthreads();

    int v = 0, s = 0;
    if (t < BT) {
        v = off[t]; s = v;
        #pragma unroll
        for (int o = 1; o < 64; o <<= 1) {
            int u = __shfl_up(s, o, 64);
            if (l >= o) s += u;
        }
        if (l == 63) wtot[w] = s;
    }
    __syncthreads();
    if (t < BT) {
        int ex = ((w == 1) ? wtot[0] : 0) + s - v;
        off[t] = ex; cur[t] = ex;
    }
    if (t == 0) off[BT] = wtot[0] + wtot[1];
    __syncthreads();

    for (int i = t; i < cnt; i += 512) {
        unsigned e = (unsigned)tmp[i];
        int pos = atomicAdd(&cur[e & (BT - 1)], 1);
        srcl[pos] = (unsigned short)(e >> 7);
    }
    __syncthreads();

    for (int i = t; i < cnt; i += 512)
        srcl_g[(size_t)bid * CAP + i] = srcl[i];
    if (t <= BT)
        off_g[(size_t)bid * (BT + 1) + t] = off[t];
}

// ---------------------------------------------------------------------------
// gemmZ: Z_l = x@Wlp (SLICE-major bf16 [4][N+1][32]), Z_r = x@Wrp + cvec.
// ---------------------------------------------------------------------------
__global__ __launch_bounds__(256)
void gemmz_kernel(const unsigned short* __restrict__ x_bf,
                  const unsigned short* __restrict__ WlpB,
                  const unsigned short* __restrict__ WrpB,
                  const float* __restrict__ cvec,
                  unsigned short* __restrict__ zl, unsigned short* __restrict__ zr,
                  int N)
{
    const int t = threadIdx.x, w = t >> 6, l = t & 63;
    const int q = l & 15, kg = l >> 4;
    const int node0 = blockIdx.x * 64 + w * 16;
    const int arow = min(node0 + q, N - 1);

    bf16x8 fx[4];
    #pragma unroll
    for (int kt = 0; kt < 4; ++kt)
        fx[kt] = *reinterpret_cast<const bf16x8*>(x_bf + (size_t)arow * D + kt * 32 + kg * 8);

    #pragma unroll
    for (int nt = 0; nt < 8; ++nt) {
        f32x4 cl = {0.f, 0.f, 0.f, 0.f};
        f32x4 cr = {0.f, 0.f, 0.f, 0.f};
        #pragma unroll
        for (int kt = 0; kt < 4; ++kt) {
            const size_t fo = ((size_t)(kt * 8 + nt) * 64 + l) * 8;
            bf16x8 wl = *reinterpret_cast<const bf16x8*>(WlpB + fo);
            bf16x8 wr = *reinterpret_cast<const bf16x8*>(WrpB + fo);
            cl = MFMA16(fx[kt], wl, cl, 0, 0, 0);
            cr = MFMA16(fx[kt], wr, cr, 0, 0, 0);
        }
        float cv = cvec[nt * 16 + q];
        const int sidx = nt >> 1;
        const int cin  = (nt & 1) * 16 + q;
        #pragma unroll
        for (int r = 0; r < 4; ++r) {
            int grow = node0 + kg * 4 + r;
            if (grow < N) {
                zl[((size_t)sidx * (N + 1) + grow) * 32 + cin] = f2bf(cl[r]);
                zr[(size_t)grow * D + nt * 16 + q]             = f2bf(cr[r] + cv);
            }
        }
    }
}

// ---------------------------------------------------------------------------
// gather v4: ASYNC-STAGED chunks + LDS segment-sum.
// Fix for r6/r9/r10 (compiler serializes dependent L2 gathers, VGPR=24):
// global_load_lds is fire-and-forget DMA (no dest VGPR -> no chain to
// serialize); consume happens from LDS at ~60cyc with 8 independent
// chains/wave. grid = 4 slices x 2 types x NBKT; slice = bid&3 keeps each
// XCD on one 3.2MB Z_l slice (L2-resident, FETCH 21MB verified r5-r10).
// Per chunk of 256 edges: 4 gload_lds instrs/wave (lane addr = row srcl[e],
// 16B sub-chunk; LDS dest linear per m104), syncthreads drains vmcnt, then
// segment-sum: lane (tg=l>>3, c8=l&7), targets t = p*32 + w*8 + tg, acc
// persists across chunks. No sentinel padding, exact bounds.
// ---------------------------------------------------------------------------
__global__ __launch_bounds__(256)
void gather_kernel(const unsigned short* __restrict__ zl,   // [4][N+1][32]
                   const unsigned short* __restrict__ srcl_g,
                   const int* __restrict__ off_g,
                   unsigned short* __restrict__ agg_a,
                   unsigned short* __restrict__ agg_b,
                   int N, int NBKT, int CAP)
{
    __shared__ int off[BT + 1];
    __shared__ unsigned short stage[CE * 32];   // 16 KB: chunk rows, 64B each

    const int bid   = blockIdx.x;
    const int slice = bid & 3;
    const int tb    = bid >> 2;
    const int type  = (tb >= NBKT);
    const int k     = tb - type * NBKT;

    const int t = threadIdx.x, l = t & 63, w = t >> 6;
    const int tg = l >> 3;                     // target chain 0..7
    const int c8 = l & 7;                      // uint2 within 64B row

    for (int i = t; i <= BT; i += 256)
        off[i] = off_g[(size_t)tb * (BT + 1) + i];
    __syncthreads();

    const int cnt = off[BT];
    const unsigned short* zs = zl + (size_t)slice * (N + 1) * 32;
    const unsigned short* sl = srcl_g + (size_t)tb * CAP;

    // my 4 targets and their full ranges
    int myt[4], mo0[4], mo1[4];
    float acc[4][4];
    #pragma unroll
    for (int p = 0; p < 4; ++p) {
        myt[p] = p * 32 + w * 8 + tg;
        mo0[p] = off[myt[p]];
        mo1[p] = off[myt[p] + 1];
        acc[p][0] = acc[p][1] = acc[p][2] = acc[p][3] = 0.f;
    }

    const int nc = (cnt + CE - 1) / CE;
    for (int c = 0; c < nc; ++c) {
        const int c0 = c * CE;
        // ---- stage: 4 x global_load_lds width16 per wave (fire-and-forget)
        #pragma unroll
        for (int i = 0; i < 4; ++i) {
            const int el = w * 64 + i * 16 + (l >> 2);     // edge in chunk
            const unsigned sid = sl[c0 + el];              // may be garbage past cnt (harmless)
            const char* g = (const char*)zs + (size_t)sid * 64 + (l & 3) * 16;
            char* ldsb = (char*)stage + (size_t)(w * 64 + i * 16) * 64;
            __builtin_amdgcn_global_load_lds(
                (const __attribute__((address_space(1))) unsigned*)g,
                (__attribute__((address_space(3))) unsigned*)ldsb, 16, 0, 0);
        }
        __syncthreads();   // drains vmcnt (compiler emits full waitcnt) -> stage ready

        // ---- segment-sum from LDS: 8 independent chains per wave
        const int c1 = c0 + CE;
        #pragma unroll
        for (int p = 0; p < 4; ++p) {
            const int lo = max(mo0[p], c0);
            const int hi = min(mo1[p], c1);
            int j = lo;
            for (; j + 1 < hi; j += 2) {
                uint2 v0 = *reinterpret_cast<const uint2*>(stage + (j - c0) * 32 + c8 * 4);
                uint2 v1 = *reinterpret_cast<const uint2*>(stage + (j + 1 - c0) * 32 + c8 * 4);
                acc[p][0] += __builtin_bit_cast(float, v0.x << 16)
                           + __builtin_bit_cast(float, v1.x << 16);
                acc[p][1] += __builtin_bit_cast(float, v0.x & 0xffff0000u)
                           + __builtin_bit_cast(float, v1.x & 0xffff0000u);
                acc[p][2] += __builtin_bit_cast(float, v0.y << 16)
                           + __builtin_bit_cast(float, v1.y << 16);
                acc[p][3] += __builtin_bit_cast(float, v0.y & 0xffff0000u)
                           + __builtin_bit_cast(float, v1.y & 0xffff0000u);
            }
            if (j < hi) {
                uint2 v0 = *reinterpret_cast<const uint2*>(stage + (j - c0) * 32 + c8 * 4);
                acc[p][0] += __builtin_bit_cast(float, v0.x << 16);
                acc[p][1] += __builtin_bit_cast(float, v0.x & 0xffff0000u);
                acc[p][2] += __builtin_bit_cast(float, v0.y << 16);
                acc[p][3] += __builtin_bit_cast(float, v0.y & 0xffff0000u);
            }
        }
        __syncthreads();   // all reads done before next chunk overwrites stage
    }

    // ---- scale + pack + store ----
    unsigned short* agg = (type ? agg_b : agg_a) + (size_t)slice * N * 32;
    #pragma unroll
    for (int p = 0; p < 4; ++p) {
        const int n = k * BT + myt[p];
        const int deg = mo1[p] - mo0[p];
        if (n < N) {
            const float r = 1.0f / fmaxf((float)deg, 1.0f);
            uint2 o;
            o.x = ((unsigned)f2bf(acc[p][1] * r) << 16) | f2bf(acc[p][0] * r);
            o.y = ((unsigned)f2bf(acc[p][3] * r) << 16) | f2bf(acc[p][2] * r);
            *reinterpret_cast<uint2*>(agg + (size_t)n * 32 + c8 * 4) = o;
        }
    }
}

// ---------------------------------------------------------------------------
// epilogue: logits_t = agg_t + Z_r; softmax, average, store f32. (verified r9)
// ---------------------------------------------------------------------------
__global__ __launch_bounds__(256)
void epi_kernel(const unsigned short* __restrict__ agg_a,
                const unsigned short* __restrict__ agg_b,
                const unsigned short* __restrict__ zr,
                float* __restrict__ out, int N)
{
    const int t = threadIdx.x;
    const int n = blockIdx.x * 16 + (t >> 4);
    const int c = t & 15;
    if (n >= N) return;

    const int s = c >> 2;
    const size_t aoff = ((size_t)s * N + n) * 32 + (c & 3) * 8;
    uint4 va = *reinterpret_cast<const uint4*>(agg_a + aoff);
    uint4 vb = *reinterpret_cast<const uint4*>(agg_b + aoff);
    uint4 vz = *reinterpret_cast<const uint4*>(zr + (size_t)n * D + c * 8);

    unsigned ua[4] = {va.x, va.y, va.z, va.w};
    unsigned ub[4] = {vb.x, vb.y, vb.z, vb.w};
    unsigned uz[4] = {vz.x, vz.y, vz.z, vz.w};

    float la[8], lb[8];
    #pragma unroll
    for (int d = 0; d < 4; ++d) {
        float z0 = __builtin_bit_cast(float, uz[d] << 16);
        float z1 = __builtin_bit_cast(float, uz[d] & 0xffff0000u);
        la[2*d]   = __builtin_bit_cast(float, ua[d] << 16) + z0;
        la[2*d+1] = __builtin_bit_cast(float, ua[d] & 0xffff0000u) + z1;
        lb[2*d]   = __builtin_bit_cast(float, ub[d] << 16) + z0;
        lb[2*d+1] = __builtin_bit_cast(float, ub[d] & 0xffff0000u) + z1;
    }

    float ma = -INFINITY, mb = -INFINITY;
    #pragma unroll
    for (int j = 0; j < 8; ++j) { ma = fmaxf(ma, la[j]); mb = fmaxf(mb, lb[j]); }
    #pragma unroll
    for (int o = 1; o < 16; o <<= 1) {
        ma = fmaxf(ma, __shfl_xor(ma, o, 64));
        mb = fmaxf(mb, __shfl_xor(mb, o, 64));
    }
    float sa = 0.f, sb = 0.f;
    #pragma unroll
    for (int j = 0; j < 8; ++j) {
        la[j] = __expf(la[j] - ma); sa += la[j];
        lb[j] = __expf(lb[j] - mb); sb += lb[j];
    }
    #pragma unroll
    for (int o = 1; o < 16; o <<= 1) {
        sa += __shfl_xor(sa, o, 64);
        sb += __shfl_xor(sb, o, 64);
    }
    const float ra = 0.5f / sa, rb = 0.5f / sb;

    float4 o0, o1;
    o0.x = la[0]*ra + lb[0]*rb; o0.y = la[1]*ra + lb[1]*rb;
    o0.z = la[2]*ra + lb[2]*rb; o0.w = la[3]*ra + lb[3]*rb;
    o1.x = la[4]*ra + lb[4]*rb; o1.y = la[5]*ra + lb[5]*rb;
    o1.z = la[6]*ra + lb[6]*rb; o1.w = la[7]*ra + lb[7]*rb;
    float* op = out + (size_t)n * D + c * 8;
    *reinterpret_cast<float4*>(op)     = o0;
    *reinterpret_cast<float4*>(op + 4) = o1;
}

// ---------------------------------------------------------------------------
extern "C" void kernel_launch(void* const* d_in, const int* in_sizes, int n_in,
                              void* d_out, int out_size, void* d_ws, size_t ws_size,
                              hipStream_t stream)
{
    const float* x  = (const float*)d_in[0];
    const float* Wl = (const float*)d_in[1];
    const float* bl = (const float*)d_in[2];
    const float* Wr = (const float*)d_in[3];
    const float* Wp = (const float*)d_in[4];
    const float* bp = (const float*)d_in[5];
    const int*   ea = (const int*)d_in[6];
    const int*   eb = (const int*)d_in[7];

    const int N  = in_sizes[0] / D;
    const int Ea = in_sizes[6] / 2;
    const int Eb = in_sizes[7] / 2;

    const int NBKT = (N + BT - 1) / BT;
    const int Emax = Ea > Eb ? Ea : Eb;
    int CAP = (int)(((long long)Emax * BT / N) * 5 / 4 + 128);
    CAP = (CAP + 7) & ~7;

    unsigned int* ent_a = (unsigned int*)d_ws;              // NBKT*CAP
    unsigned int* ent_b = ent_a + (size_t)NBKT * CAP;
    int* cnt_a = (int*)(ent_b + (size_t)NBKT * CAP);        // NBKT
    int* cnt_b = cnt_a + NBKT;
    int* off_g = cnt_b + NBKT;                              // 2*NBKT*(BT+1)
    float* cvec = (float*)(off_g + (size_t)2 * NBKT * (BT + 1));  // 128
    uintptr_t p = (uintptr_t)(cvec + 128);
    p = (p + 15) & ~(uintptr_t)15;
    unsigned short* srcl_g = (unsigned short*)p;            // 2*NBKT*CAP + slack
    unsigned short* x_bf   = srcl_g + (size_t)2 * NBKT * CAP + 512;
    unsigned short* zl     = x_bf + (size_t)N * D;          // [4][N+1][32]
    unsigned short* zr     = zl + (size_t)4 * (N + 1) * 32;
    unsigned short* agg_a  = zr + (size_t)N * D;            // [4][N][32]
    unsigned short* agg_b  = agg_a + (size_t)N * D;
    unsigned short* WlpB   = agg_b + (size_t)N * D;
    unsigned short* WrpB   = WlpB + D * D;

    hipMemsetAsync(cnt_a, 0, sizeof(int) * 2 * (size_t)NBKT, stream);

    wprod_kernel<<<16, 256, 0, stream>>>(Wl, Wr, Wp, bl, bp, WlpB, WrpB, cvec);

    const int GA = (Ea + TILE - 1) / TILE;
    const int GB = (Eb + TILE - 1) / TILE;
    const int GCONV = 512;
    prep_kernel<<<GA + GB + GCONV, 256, 0, stream>>>(
        x, x_bf, ea, Ea, eb, Eb, ent_a, cnt_a, ent_b, cnt_b,
        N, NBKT, CAP, GA, GB, GCONV);

    const int smem_sort = CAP * 6 + (BT + 1 + BT + 2) * 4 + 16;
    sort_kernel<<<2 * NBKT, 512, smem_sort, stream>>>(
        ent_a, cnt_a, ent_b, cnt_b, srcl_g, off_g, NBKT, CAP);

    gemmz_kernel<<<(N + 63) / 64, 256, 0, stream>>>(
        x_bf, WlpB, WrpB, cvec, zl, zr, N);

    gather_kernel<<<8 * NBKT, 256, 0, stream>>>(
        zl, srcl_g, off_g, agg_a, agg_b, N, NBKT, CAP);

    epi_kernel<<<(N + 15) / 16, 256, 0, stream>>>(agg_a, agg_b, zr,
                                                  (float*)d_out, N);
}